// Round 2
// baseline (21189.102 us; speedup 1.0000x reference)
//
#include <hip/hip_runtime.h>
#include <hip/hip_bf16.h>

// Persistent wavefront-pipelined 3-layer LSTM + projection for MI355X.
// R2: producer-consumer flag sync (no global barrier), agent-scope atomic
// ring traffic (no cache-op fences in loop), launch_bounds(512,1) so the
// 96-VGPR weight fragments stay resident, 6-chunk load prefetch window.

#define T_SEQ 1024
#define NB    64
#define HIDN  768
#define INW   512
#define NOUT  100
#define NWG   145

typedef unsigned int u32;
typedef unsigned short u16;
typedef unsigned long long u64;
typedef short bf16x8 __attribute__((ext_vector_type(8)));
typedef float f32x4  __attribute__((ext_vector_type(4)));

// ---- ws layout ----
#define OFF_WIH1 0
#define OFF_WHH1 1572864     // 3072*512
#define OFF_WIH2 3932160
#define OFF_WHH2 6291456
#define OFF_WIH3 8650752
#define OFF_WHH3 11010048
#define OFF_WP   13369344
#define W_TOTAL  13455360    // + 112*768 (Wp padded)
#define RING_BYTE_OFF (W_TOTAL * 2)
#define SLOT_ELEMS 49152                       // 64*768 bf16
#define RING_DEPTH 4
#define RING_ELEMS (RING_DEPTH * SLOT_ELEMS)
#define RINGS_BYTES (5 * RING_ELEMS * 2)       // 1,966,080
#define FLAGS_BYTES (4 * 1024 * 64 * 4)        // 1,048,576

__device__ __forceinline__ u16 f2b(float f) {
  u32 x = __builtin_bit_cast(u32, f);
  x += 0x7fff + ((x >> 16) & 1);
  return (u16)(x >> 16);
}
__device__ __forceinline__ float b2f(u16 u) {
  u32 x = ((u32)u) << 16;
  return __builtin_bit_cast(float, x);
}
__device__ __forceinline__ u32 pack2(float lo, float hi) {
  return (u32)f2b(lo) | ((u32)f2b(hi) << 16);
}
__device__ __forceinline__ float sigf(float x) { return 1.f / (1.f + __expf(-x)); }
__device__ __forceinline__ float tanhf_(float x) {
  float e = __expf(-2.f * fabsf(x));
  float r = (1.f - e) / (1.f + e);
  return x >= 0.f ? r : -r;
}

__global__ void prep_weights(const float* __restrict__ Wih1, const float* __restrict__ Whh1,
                             const float* __restrict__ Wih2, const float* __restrict__ Whh2,
                             const float* __restrict__ Wih3, const float* __restrict__ Whh3,
                             const float* __restrict__ Wp, u16* __restrict__ wb) {
  int i = blockIdx.x * 256 + threadIdx.x;
  if (i >= W_TOTAL) return;
  float v;
  if (i < OFF_WHH1)      v = Wih1[i];
  else if (i < OFF_WIH2) v = Whh1[i - OFF_WHH1];
  else if (i < OFF_WHH2) v = Wih2[i - OFF_WIH2];
  else if (i < OFF_WIH3) v = Whh2[i - OFF_WHH2];
  else if (i < OFF_WHH3) v = Wih3[i - OFF_WIH3];
  else if (i < OFF_WP)   v = Whh3[i - OFF_WHH3];
  else {
    int j = i - OFF_WP;
    v = (j < NOUT * HIDN) ? Wp[j] : 0.f;
  }
  wb[i] = f2b(v);
}

struct __align__(16) SharedMem {
  u16   Ach[2][64 * 128];   // 32 KB double-buffered A chunk, XOR atom swizzle
  float Xg[8 * 1088];       // 34.8 KB gate exchange, stride 17 (pad) per b-row
  float c_lds[1024];        // fp32 cell state [b][j]
  float bias_lds[64];       // [gate][j]
};

template <int STAGE>
__device__ void stage_loop(SharedMem* sm,
                           const float* __restrict__ x,
                           const float* __restrict__ bias,
                           const u16* __restrict__ Wlo,     // Wih_l (or Wp)
                           const u16* __restrict__ Whi,     // Whh_l
                           const u16* __restrict__ ringIn,
                           u16* __restrict__ ringOwn,
                           u16* __restrict__ ringSum,
                           float* __restrict__ out,
                           u32* __restrict__ flags, int wgl, int j0) {
  constexpr int NCH = (STAGE == 0) ? 10 : (STAGE == 3 ? 6 : 12);
  constexpr int PF  = 6;
  constexpr int NKT = (STAGE == 0) ? 20 : 24;

  const int tid  = threadIdx.x;
  const int lane = tid & 63;
  const int w    = tid >> 6;
  const int l15  = lane & 15;
  const int q    = lane >> 4;
  const int g    = w & 3;   // gate
  const int kh   = w >> 2;  // K-half

  // per-wave poll condition (wave w polls one flag row)
  int myCS = -1, myDt = 0, myNp = 48;
  if constexpr (STAGE == 0) {
    if (w == 0) { myCS = 0; myDt = -1; }         // own h(t-1)
    else if (w == 1) { myCS = 1; myDt = -4; }    // backpressure: L2 done t-4
  } else if constexpr (STAGE == 1) {
    if (w == 0) { myCS = 1; myDt = -1; }
    else if (w == 1) { myCS = 0; myDt = 0; }     // input ring1[t]
    else if (w == 2) { myCS = 2; myDt = -4; }
  } else if constexpr (STAGE == 2) {
    if (w == 0) { myCS = 2; myDt = -1; }
    else if (w == 1) { myCS = 1; myDt = 0; }
    else if (w == 2) { myCS = 3; myDt = -4; myNp = 1; }
  } else {
    if (w == 0) { myCS = 2; myDt = 0; }
  }

  if constexpr (STAGE < 3) {
    sm->c_lds[tid] = 0.f;
    sm->c_lds[tid + 512] = 0.f;
    if (tid < 64) sm->bias_lds[tid] = bias[(tid >> 4) * HIDN + j0 + (tid & 15)];
  }
  __syncthreads();

  // ---- resident B fragments ----
  // STAGE0: chunks 0..4 = h k[0:640] (kh0), 5 = h k[640:768] (kh1),
  //         6..9 = x k[0:512] (kh1).  STAGE1/2: 0..5 own-h (kh1), 6..11 input (kh0).
  bf16x8 bfrag[NKT];
  if constexpr (STAGE == 0) {
    int nrow = g * HIDN + j0 + l15;
#pragma unroll
    for (int kt = 0; kt < 20; ++kt) {
      const u16* p;
      if (kh == 0)      p = Whi + (size_t)nrow * HIDN + kt * 32 + q * 8;            // Whh k 0..639
      else if (kt < 4)  p = Whi + (size_t)nrow * HIDN + 640 + kt * 32 + q * 8;      // Whh k 640..767
      else              p = Wlo + (size_t)nrow * INW + (kt - 4) * 32 + q * 8;       // Wih k 0..511
      bfrag[kt] = *(const bf16x8*)p;
    }
  } else if constexpr (STAGE == 3) {
    int nrow = w * 16 + l15; if (nrow > 111) nrow = 111;
#pragma unroll
    for (int kt = 0; kt < 24; ++kt)
      bfrag[kt] = *(const bf16x8*)(Wlo + (size_t)nrow * HIDN + kt * 32 + q * 8);
  } else {
    int nrow = g * HIDN + j0 + l15;
#pragma unroll
    for (int kt = 0; kt < 24; ++kt) {
      const u16* p = (kh == 1) ? (Whi + (size_t)nrow * HIDN + kt * 32 + q * 8)      // own-h
                               : (Wlo + (size_t)nrow * HIDN + kt * 32 + q * 8);     // input
      bfrag[kt] = *(const bf16x8*)p;
    }
  }

  auto load_chunk = [&](int c, int t, uint4* vv) {
#pragma unroll
    for (int rep = 0; rep < 2; ++rep) {
      int id = tid + rep * 512;
      int r = id >> 4, a = id & 15;
      bool isx = false;
      if constexpr (STAGE == 0) isx = (c >= 6);
      if (isx) {
        const float* xp = x + ((size_t)r * T_SEQ + t) * INW + (c - 6) * 128 + a * 8;
        float4 f0 = *(const float4*)xp;
        float4 f1 = *(const float4*)(xp + 4);
        uint4 v;
        v.x = pack2(f0.x, f0.y); v.y = pack2(f0.z, f0.w);
        v.z = pack2(f1.x, f1.y); v.w = pack2(f1.z, f1.w);
        vv[rep] = v;
      } else {
        const u16* src; int koff;
        if constexpr (STAGE == 0)      { src = ringOwn + ((t - 1) & 3) * SLOT_ELEMS; koff = c * 128; }
        else if constexpr (STAGE == 3) { src = ringIn + (t & 3) * SLOT_ELEMS; koff = c * 128; }
        else {
          if (c < 6) { src = ringOwn + ((t - 1) & 3) * SLOT_ELEMS; koff = c * 128; }
          else       { src = ringIn + (t & 3) * SLOT_ELEMS; koff = (c - 6) * 128; }
        }
        const u64* p = (const u64*)(src + (size_t)r * HIDN + koff + a * 8);
        u64 lo = __hip_atomic_load(p,     __ATOMIC_RELAXED, __HIP_MEMORY_SCOPE_AGENT);
        u64 hi = __hip_atomic_load(p + 1, __ATOMIC_RELAXED, __HIP_MEMORY_SCOPE_AGENT);
        uint4 v;
        v.x = (u32)lo; v.y = (u32)(lo >> 32); v.z = (u32)hi; v.w = (u32)(hi >> 32);
        vv[rep] = v;
      }
    }
  };

  auto write_chunk = [&](int buf, const uint4* vv) {
    u16* dst = sm->Ach[buf];
#pragma unroll
    for (int rep = 0; rep < 2; ++rep) {
      int id = tid + rep * 512;
      int r = id >> 4, a = id & 15;
      int sa = a ^ (r & 7);
      *(uint4*)((char*)dst + r * 256 + sa * 16) = vv[rep];
    }
  };

  for (int t = 0; t < T_SEQ; ++t) {
    // ---- wave-parallel flag poll ----
    if (myCS >= 0) {
      int rt = t + myDt;
      if (rt >= 0) {
        const u32* row = flags + (((size_t)myCS << 10) + rt) * 64;
        const u32* pp = row + (lane < myNp ? lane : 0);
        while (true) {
          u32 v = __hip_atomic_load(pp, __ATOMIC_RELAXED, __HIP_MEMORY_SCOPE_AGENT);
          if (__all(v != 0)) break;
          __builtin_amdgcn_s_sleep(1);
        }
      }
    }
    __syncthreads();

    f32x4 acc[4];
#pragma unroll
    for (int mt = 0; mt < 4; ++mt) acc[mt] = (f32x4){0.f, 0.f, 0.f, 0.f};

    uint4 win[PF][2];
#pragma unroll
    for (int c0 = 0; c0 < PF; ++c0)
      if (c0 < NCH) load_chunk(c0, t, win[c0]);
    write_chunk(0, win[0]);
    if constexpr (PF < NCH) load_chunk(PF, t, win[0]);
    __syncthreads();

#pragma unroll
    for (int c = 0; c < NCH; ++c) {
      if (c + 1 < NCH) {
        write_chunk((c + 1) & 1, win[(c + 1) % PF]);
        if (c + 1 + PF < NCH) load_chunk(c + 1 + PF, t, win[(c + 1) % PF]);
      }
      bool mine;
      if constexpr (STAGE == 3)      mine = (w < 7);
      else if constexpr (STAGE == 0) mine = (kh == 0) ? (c < 5) : (c >= 5);
      else                           mine = (kh == 1) ? (c < 6) : (c >= 6);
      if (mine) {
        int kbase;
        if constexpr (STAGE == 0)      kbase = (kh == 0) ? c * 4 : (c == 5 ? 0 : 4 + (c - 6) * 4);
        else if constexpr (STAGE == 3) kbase = c * 4;
        else                           kbase = (kh == 1) ? c * 4 : (c - 6) * 4;
        const char* Ab = (const char*)sm->Ach[c & 1];
#pragma unroll
        for (int kt2 = 0; kt2 < 4; ++kt2) {
          bf16x8 af[4];
#pragma unroll
          for (int mt = 0; mt < 4; ++mt) {
            int r = mt * 16 + l15;
            int a = kt2 * 4 + q;
            int sa = a ^ (r & 7);
            af[mt] = *(const bf16x8*)(Ab + r * 256 + sa * 16);
          }
#pragma unroll
          for (int mt = 0; mt < 4; ++mt)
            acc[mt] = __builtin_amdgcn_mfma_f32_16x16x32_bf16(af[mt], bfrag[kbase + kt2], acc[mt], 0, 0, 0);
        }
      }
      __syncthreads();
    }

    if constexpr (STAGE < 3) {
      // K-half reduction (padded stride 17 to dodge bank conflicts)
      if (kh == 1) {
#pragma unroll
        for (int mt = 0; mt < 4; ++mt)
#pragma unroll
          for (int i = 0; i < 4; ++i)
            sm->Xg[(4 + g) * 1088 + (mt * 16 + q * 4 + i) * 17 + l15] = acc[mt][i];
      }
      __syncthreads();
      if (kh == 0) {
#pragma unroll
        for (int mt = 0; mt < 4; ++mt)
#pragma unroll
          for (int i = 0; i < 4; ++i) {
            int idx = (mt * 16 + q * 4 + i) * 17 + l15;
            sm->Xg[g * 1088 + idx] = acc[mt][i] + sm->Xg[(4 + g) * 1088 + idx];
          }
      }
      __syncthreads();
      // gate math + ring writes (agent-scope atomic stores: write-through)
      {
        int b = tid >> 3, jp = tid & 7;
        float hv[2];
#pragma unroll
        for (int u2 = 0; u2 < 2; ++u2) {
          int j = jp * 2 + u2;
          float pi = sm->Xg[0 * 1088 + b * 17 + j] + sm->bias_lds[j];
          float pf = sm->Xg[1 * 1088 + b * 17 + j] + sm->bias_lds[16 + j];
          float pg = sm->Xg[2 * 1088 + b * 17 + j] + sm->bias_lds[32 + j];
          float po = sm->Xg[3 * 1088 + b * 17 + j] + sm->bias_lds[48 + j];
          float ig = sigf(pi), fg = sigf(pf), gv = tanhf_(pg), og = sigf(po);
          float cc = fg * sm->c_lds[b * 16 + j] + ig * gv;
          sm->c_lds[b * 16 + j] = cc;
          hv[u2] = og * tanhf_(cc);
        }
        int dw = (b * HIDN + j0 + jp * 2) >> 1;
        u32* ownw = (u32*)(ringOwn + (t & 3) * SLOT_ELEMS);
        __hip_atomic_store(ownw + dw, pack2(hv[0], hv[1]), __ATOMIC_RELAXED, __HIP_MEMORY_SCOPE_AGENT);
        if constexpr (STAGE == 1 || STAGE == 2) {
          const u32* resr = (const u32*)(ringIn + (t & 3) * SLOT_ELEMS);
          u32 rv = __hip_atomic_load(resr + dw, __ATOMIC_RELAXED, __HIP_MEMORY_SCOPE_AGENT);
          float s0 = b2f((u16)(rv & 0xffffu)) + hv[0];
          float s1 = b2f((u16)(rv >> 16)) + hv[1];
          __hip_atomic_store(((u32*)(ringSum + (t & 3) * SLOT_ELEMS)) + dw, pack2(s0, s1),
                             __ATOMIC_RELAXED, __HIP_MEMORY_SCOPE_AGENT);
        }
      }
    } else {
      if (w < 7) {
#pragma unroll
        for (int mt = 0; mt < 4; ++mt)
#pragma unroll
          for (int i = 0; i < 4; ++i) {
            int b = mt * 16 + q * 4 + i;
            int n = w * 16 + l15;
            if (n < NOUT)
              out[((size_t)b * T_SEQ + t) * NOUT + n] = acc[mt][i];
          }
      }
    }

    // ---- release + per-WG flag ----
    __builtin_amdgcn_fence(__ATOMIC_RELEASE, "agent");   // drain this wave's stores
    __syncthreads();
    if (tid == 0)
      __hip_atomic_store(flags + (((size_t)STAGE << 10) + t) * 64 + wgl, 1u,
                         __ATOMIC_RELAXED, __HIP_MEMORY_SCOPE_AGENT);
  }
}

__global__ __launch_bounds__(512, 1) void lstm_main(
    const float* __restrict__ x,
    const float* __restrict__ b1, const float* __restrict__ b2, const float* __restrict__ b3,
    const u16* __restrict__ wb, u16* __restrict__ rings, u32* __restrict__ flags,
    float* __restrict__ out) {
  __shared__ SharedMem sm;
  const int wg = blockIdx.x;
  const u16* Wih1b = wb + OFF_WIH1;
  const u16* Whh1b = wb + OFF_WHH1;
  const u16* Wih2b = wb + OFF_WIH2;
  const u16* Whh2b = wb + OFF_WHH2;
  const u16* Wih3b = wb + OFF_WIH3;
  const u16* Whh3b = wb + OFF_WHH3;
  const u16* Wpb   = wb + OFF_WP;
  u16* ring1  = rings;
  u16* ring2  = rings + 1 * RING_ELEMS;
  u16* ringS2 = rings + 2 * RING_ELEMS;
  u16* ring3  = rings + 3 * RING_ELEMS;
  u16* ringS3 = rings + 4 * RING_ELEMS;
  if (wg < 48)
    stage_loop<0>(&sm, x, b1, Wih1b, Whh1b, nullptr, ring1, nullptr, nullptr,
                  flags, wg, wg * 16);
  else if (wg < 96)
    stage_loop<1>(&sm, nullptr, b2, Wih2b, Whh2b, ring1, ring2, ringS2, nullptr,
                  flags, wg - 48, (wg - 48) * 16);
  else if (wg < 144)
    stage_loop<2>(&sm, nullptr, b3, Wih3b, Whh3b, ringS2, ring3, ringS3, nullptr,
                  flags, wg - 96, (wg - 96) * 16);
  else
    stage_loop<3>(&sm, nullptr, nullptr, Wpb, nullptr, ringS3, nullptr, nullptr,
                  (float*)out, flags, 0, 0);
}

extern "C" void kernel_launch(void* const* d_in, const int* in_sizes, int n_in,
                              void* d_out, int out_size, void* d_ws, size_t ws_size,
                              hipStream_t stream) {
  (void)in_sizes; (void)n_in; (void)out_size; (void)ws_size;
  const float* x    = (const float*)d_in[0];
  const float* Wih1 = (const float*)d_in[1];
  const float* Whh1 = (const float*)d_in[2];
  const float* b1   = (const float*)d_in[3];
  const float* Wih2 = (const float*)d_in[4];
  const float* Whh2 = (const float*)d_in[5];
  const float* b2   = (const float*)d_in[6];
  const float* Wih3 = (const float*)d_in[7];
  const float* Whh3 = (const float*)d_in[8];
  const float* b3   = (const float*)d_in[9];
  const float* Wp   = (const float*)d_in[10];

  char* base  = (char*)d_ws;
  u16*  wb    = (u16*)base;
  u16*  rings = (u16*)(base + RING_BYTE_OFF);
  u32*  flags = (u32*)(base + RING_BYTE_OFF + RINGS_BYTES);

  hipMemsetAsync(base + RING_BYTE_OFF, 0, RINGS_BYTES + FLAGS_BYTES, stream);

  prep_weights<<<(W_TOTAL + 255) / 256, 256, 0, stream>>>(Wih1, Whh1, Wih2, Whh2, Wih3, Whh3, Wp, wb);

  lstm_main<<<NWG, 512, 0, stream>>>(x, b1, b2, b3, wb, rings, flags, (float*)d_out);
}